// Round 2
// baseline (1940.134 us; speedup 1.0000x reference)
//
#include <hip/hip_runtime.h>

typedef __bf16 bf16;
typedef __attribute__((ext_vector_type(8))) __bf16 bf16x8;
typedef __attribute__((ext_vector_type(4))) __bf16 bf16x4;
typedef __attribute__((ext_vector_type(4))) float f32x4;

#define GL16(gp, lp) __builtin_amdgcn_global_load_lds( \
    (const __attribute__((address_space(1))) unsigned int*)(gp), \
    (__attribute__((address_space(3))) unsigned int*)(lp), 16, 0, 0)

__device__ __forceinline__ f32x4 mfma16(bf16x8 a, bf16x8 b, f32x4 c) {
  return __builtin_amdgcn_mfma_f32_16x16x32_bf16(a, b, c, 0, 0, 0);
}

// ---------------------------------------------------------------------------
// Generic bf16 GEMM: C[M][N] = A[M][K] (bf16, row-major) * Bt[N][K]^T (bf16)
// 128x128 tile, BK=32, 4 waves (2x2 of 64x64), global_load_lds staging.
// Optional bias (fp32 [N]), residual (fp32 [M][N]), ReLU; out fp32 or bf16.
// ---------------------------------------------------------------------------
template<int RELU, int BIAS, int RES, int OUTB>
__global__ __launch_bounds__(256, 2) void gemm_k(
    const bf16* __restrict__ A, const bf16* __restrict__ Bt,
    float* __restrict__ Cf, bf16* __restrict__ Cb,
    const float* __restrict__ bias, const float* __restrict__ resid,
    int M, int N, int K)
{
  __shared__ __align__(16) bf16 Al[128 * 32];
  __shared__ __align__(16) bf16 Bl[128 * 32];
  const int tid = threadIdx.x;
  const int wid = tid >> 6, lane = tid & 63;
  const int g = lane >> 4, l16 = lane & 15;
  const int bm = blockIdx.y * 128, bn = blockIdx.x * 128;
  const int wm = (wid >> 1) * 64, wn = (wid & 1) * 64;

  const f32x4 z4 = {0.f, 0.f, 0.f, 0.f};
  f32x4 acc[4][4];
#pragma unroll
  for (int i = 0; i < 4; ++i)
#pragma unroll
    for (int j = 0; j < 4; ++j) acc[i][j] = z4;

  // staging map: per wave-pass, lane i covers LDS bytes [wid*1024 + i*16)
  const int srow = wid * 16 + (lane >> 2);   // 0..63
  const int scol = (lane & 3) * 8;           // 0,8,16,24
  const bf16* Ag = A + (size_t)(bm + srow) * K + scol;
  const bf16* Bg = Bt + (size_t)(bn + srow) * K + scol;
  bf16* Ald = &Al[srow * 32 + scol];
  bf16* Bld = &Bl[srow * 32 + scol];
  const size_t half = (size_t)64 * K;

  for (int k0 = 0; k0 < K; k0 += 32) {
    __syncthreads();
    GL16(Ag + k0, Ald);
    GL16(Ag + k0 + half, Ald + 64 * 32);
    GL16(Bg + k0, Bld);
    GL16(Bg + k0 + half, Bld + 64 * 32);
    __syncthreads();
    bf16x8 af[4], bfr[4];
#pragma unroll
    for (int mi = 0; mi < 4; ++mi)
      af[mi] = *(const bf16x8*)&Al[(wm + mi * 16 + l16) * 32 + g * 8];
#pragma unroll
    for (int ni = 0; ni < 4; ++ni)
      bfr[ni] = *(const bf16x8*)&Bl[(wn + ni * 16 + l16) * 32 + g * 8];
#pragma unroll
    for (int mi = 0; mi < 4; ++mi)
#pragma unroll
      for (int ni = 0; ni < 4; ++ni)
        acc[mi][ni] = mfma16(af[mi], bfr[ni], acc[mi][ni]);
  }

#pragma unroll
  for (int mi = 0; mi < 4; ++mi) {
#pragma unroll
    for (int ni = 0; ni < 4; ++ni) {
#pragma unroll
      for (int r = 0; r < 4; ++r) {
        const int row = bm + wm + mi * 16 + g * 4 + r;
        const int col = bn + wn + ni * 16 + l16;
        float v = acc[mi][ni][r];
        if (BIAS) v += bias[col];
        if (RES)  v += resid[(size_t)row * N + col];
        if (RELU) v = fmaxf(v, 0.f);
        const size_t idx = (size_t)row * N + col;
        if (OUTB) Cb[idx] = (bf16)v;
        else      Cf[idx] = v;
      }
    }
  }
}

// ---------------------------------------------------------------------------
// Flash attention, MFMA, barrier-free. One block = (b, h, 64-row q tile),
// 4 independent waves x 16 q rows. KV tiles of 64. K fragments read directly
// from global ([t][dh], contraction dim contiguous). V read from precomputed
// global V^T [b*8+h][64 dh][512 t]. P staged in per-wave LDS with XOR swizzle
// (byte ^= (row&7)<<4) on both the 2B writes and the ds_read_b128 reads.
// ---------------------------------------------------------------------------
template<int CAUSAL>
__global__ __launch_bounds__(256, 4) void attn_k(
    const bf16* __restrict__ Q, const bf16* __restrict__ Kg,
    const bf16* __restrict__ VT, bf16* __restrict__ O, int qs, int kvs)
{
  __shared__ __align__(16) bf16 plb[4 * 16 * 64];   // per-wave P, swizzled
  const int tid = threadIdx.x;
  const int wid = tid >> 6, lane = tid & 63;
  const int g = lane >> 4, l16 = lane & 15;
  const int b = blockIdx.z, h = blockIdx.y;
  const int q0 = blockIdx.x * 64 + wid * 16;
  const size_t tokQ = (size_t)b * 512 + q0;

  const bf16* qp = Q + (tokQ + l16) * (size_t)qs + h * 64 + g * 8;
  const bf16x8 qf0 = *(const bf16x8*)qp;
  const bf16x8 qf1 = *(const bf16x8*)(qp + 32);
  const bf16* Kb = Kg + (size_t)b * 512 * kvs + h * 64;
  const bf16* VTb = VT + (size_t)(b * 8 + h) * 64 * 512;
  bf16* pw = plb + wid * 1024;

  const f32x4 z4 = {0.f, 0.f, 0.f, 0.f};
  float m[4], ls[4];
  f32x4 o[4];
#pragma unroll
  for (int r = 0; r < 4; ++r) { m[r] = -1e30f; ls[r] = 0.f; o[r] = z4; }

  const int ktmax = CAUSAL ? (int)blockIdx.x : 7;
  for (int kt = 0; kt <= ktmax; ++kt) {
    const int t0 = kt * 64;
    // QK^T -> 4 16x16 tiles per wave (t cols t0 + jt*16 + l16)
    f32x4 sc[4];
#pragma unroll
    for (int jt = 0; jt < 4; ++jt) sc[jt] = z4;
#pragma unroll
    for (int jt = 0; jt < 4; ++jt) {
      const bf16* kp = Kb + (size_t)(t0 + jt * 16 + l16) * kvs + g * 8;
      sc[jt] = mfma16(qf0, *(const bf16x8*)kp, sc[jt]);
      sc[jt] = mfma16(qf1, *(const bf16x8*)(kp + 32), sc[jt]);
    }
    // online softmax per row r (row q = g*4+r, col = jt*16+l16)
#pragma unroll
    for (int r = 0; r < 4; ++r) {
      const int q = g * 4 + r;
      const int srow = q0 + q;
      const int qs7 = (q & 7) << 4;
      float pv[4];
      float mx = -1e30f;
#pragma unroll
      for (int jt = 0; jt < 4; ++jt) {
        float v = sc[jt][r] * 0.125f;   // 1/sqrt(64)
        if (CAUSAL && (t0 + jt * 16 + l16) > srow) v = -1e30f;
        pv[jt] = v;
        mx = fmaxf(mx, v);
      }
#pragma unroll
      for (int msk = 8; msk; msk >>= 1) mx = fmaxf(mx, __shfl_xor(mx, msk));
      const float mn = fmaxf(m[r], mx);
      const float corr = __expf(m[r] - mn);
      float s = 0.f;
#pragma unroll
      for (int jt = 0; jt < 4; ++jt) {
        const float p = __expf(pv[jt] - mn);
        s += p;
        const int sb = (((jt * 16 + l16) * 2) ^ qs7) >> 1;
        pw[q * 64 + sb] = (bf16)p;
      }
#pragma unroll
      for (int msk = 8; msk; msk >>= 1) s += __shfl_xor(s, msk);
      ls[r] = ls[r] * corr + s;
      m[r] = mn;
#pragma unroll
      for (int j = 0; j < 4; ++j) o[j][r] *= corr;
    }
    // same-wave LDS visibility (no cross-wave sharing -> no s_barrier)
    asm volatile("s_waitcnt lgkmcnt(0)" ::: "memory");
    __builtin_amdgcn_sched_barrier(0);
    const int rs = (l16 & 7) << 4;
    const bf16x8 pa0 = *(const bf16x8*)&pw[l16 * 64 + (((g * 16) ^ rs) >> 1)];
    const bf16x8 pa1 = *(const bf16x8*)&pw[l16 * 64 + (((g * 16 + 64) ^ rs) >> 1)];
#pragma unroll
    for (int j = 0; j < 4; ++j) {
      const bf16* vp = VTb + (size_t)(j * 16 + l16) * 512 + t0 + g * 8;
      const bf16x8 vf0 = *(const bf16x8*)vp;
      const bf16x8 vf1 = *(const bf16x8*)(vp + 32);
      o[j] = mfma16(pa0, vf0, o[j]);
      o[j] = mfma16(pa1, vf1, o[j]);
    }
  }
#pragma unroll
  for (int r = 0; r < 4; ++r) {
    const float inv = 1.f / ls[r];
    bf16* op = O + (tokQ + g * 4 + r) * 512 + h * 64;
#pragma unroll
    for (int j = 0; j < 4; ++j) op[j * 16 + l16] = (bf16)(o[j][r] * inv);
  }
}

// ---------------------------------------------------------------------------
// V^T precompute: src = V rows [t][dh] (row stride `stride`, head offset
// applied by caller pointer), dst = VT [b*8+h][64 dh][512 t].
// Grid (8 t-tiles, 1, 128 bh), block (64,4).
// ---------------------------------------------------------------------------
__global__ void vtrans(const bf16* __restrict__ src, bf16* __restrict__ dst,
                       int stride)
{
  __shared__ bf16 t[64][65];
  const int bh = blockIdx.z;
  const int b = bh >> 3, h = bh & 7;
  const int t0 = blockIdx.x * 64;
  const int tx = threadIdx.x, ty = threadIdx.y;
  src += ((size_t)b * 512 + t0) * stride + h * 64;
  dst += (size_t)bh * 64 * 512 + t0;
#pragma unroll
  for (int j = 0; j < 64; j += 4)
    t[ty + j][tx] = src[(size_t)(ty + j) * stride + tx];
  __syncthreads();
#pragma unroll
  for (int j = 0; j < 64; j += 4)
    dst[(size_t)(ty + j) * 512 + tx] = t[tx][ty + j];
}

// ---------------------------------------------------------------------------
// LayerNorm over D=512. One wave per row; writes fp32 and (optional) bf16.
// ---------------------------------------------------------------------------
__global__ __launch_bounds__(256) void ln_k(
    const float* __restrict__ z, const float* __restrict__ gam,
    const float* __restrict__ bet, float* __restrict__ of,
    bf16* __restrict__ ob)
{
  const int wid = threadIdx.x >> 6, lane = threadIdx.x & 63;
  const int row = blockIdx.x * 4 + wid;
  const f32x4* zr = (const f32x4*)(z + (size_t)row * 512);
  const f32x4 a = zr[lane], c = zr[lane + 64];
  float s = 0.f, ss = 0.f;
#pragma unroll
  for (int e = 0; e < 4; ++e) {
    s += a[e] + c[e];
    ss += a[e] * a[e] + c[e] * c[e];
  }
#pragma unroll
  for (int msk = 32; msk; msk >>= 1) {
    s += __shfl_xor(s, msk);
    ss += __shfl_xor(ss, msk);
  }
  const float mean = s * (1.f / 512.f);
  const float var = ss * (1.f / 512.f) - mean * mean;
  const float rstd = rsqrtf(var + 1e-5f);
  const f32x4* gp = (const f32x4*)gam;
  const f32x4* bp = (const f32x4*)bet;
  const f32x4 g0 = gp[lane], g1 = gp[lane + 64];
  const f32x4 b0 = bp[lane], b1 = bp[lane + 64];
  f32x4 o0, o1;
#pragma unroll
  for (int e = 0; e < 4; ++e) {
    o0[e] = (a[e] - mean) * rstd * g0[e] + b0[e];
    o1[e] = (c[e] - mean) * rstd * g1[e] + b1[e];
  }
  f32x4* ofr = (f32x4*)(of + (size_t)row * 512);
  ofr[lane] = o0;
  ofr[lane + 64] = o1;
  if (ob) {
    bf16x4 c0, c1;
#pragma unroll
    for (int e = 0; e < 4; ++e) { c0[e] = (bf16)o0[e]; c1[e] = (bf16)o1[e]; }
    bf16x4* obr = (bf16x4*)(ob + (size_t)row * 512);
    obr[lane] = c0;
    obr[lane + 64] = c1;
  }
}

// ---------------------------------------------------------------------------
// Tiled transpose + fp32->bf16 cast: per batch z, src [R][C] -> dst [C][R].
// dst block offset = (z/bpl)*lstride + (z%bpl)*R*C + boff.
// ---------------------------------------------------------------------------
__global__ void transpose_cast(const float* __restrict__ src, bf16* __restrict__ dst,
                               int R, int C, int bpl, size_t lstride, size_t boff)
{
  __shared__ float t[32][33];
  const int z = blockIdx.z;
  src += (size_t)z * R * C;
  dst += (size_t)(z / bpl) * lstride + (size_t)(z % bpl) * ((size_t)R * C) + boff;
  const int c0 = blockIdx.x * 32, r0 = blockIdx.y * 32;
  const int tx = threadIdx.x, ty = threadIdx.y;   // (32, 8)
#pragma unroll
  for (int j = 0; j < 32; j += 8)
    t[ty + j][tx] = src[(size_t)(r0 + ty + j) * C + c0 + tx];
  __syncthreads();
#pragma unroll
  for (int j = 0; j < 32; j += 8)
    dst[(size_t)(c0 + ty + j) * R + r0 + tx] = (bf16)t[tx][ty + j];
}

__global__ void cast4(const float* __restrict__ s, bf16* __restrict__ d)
{
  const int i = blockIdx.x * 256 + threadIdx.x;
  const f32x4 v = ((const f32x4*)s)[i];
  bf16x4 c;
#pragma unroll
  for (int e = 0; e < 4; ++e) c[e] = (bf16)v[e];
  ((bf16x4*)d)[i] = c;
}

// ---------------------------------------------------------------------------
extern "C" void kernel_launch(void* const* d_in, const int* in_sizes, int n_in,
                              void* d_out, int out_size, void* d_ws, size_t ws_size,
                              hipStream_t stream)
{
  (void)in_sizes; (void)n_in; (void)out_size; (void)ws_size;
  const float* x   = (const float*)d_in[0];
  const float* y   = (const float*)d_in[1];
  const float* Wq1 = (const float*)d_in[2];
  const float* Wk1 = (const float*)d_in[3];
  const float* Wv1 = (const float*)d_in[4];
  const float* Wo1 = (const float*)d_in[5];
  const float* Wq2 = (const float*)d_in[6];
  const float* Wk2 = (const float*)d_in[7];
  const float* Wv2 = (const float*)d_in[8];
  const float* Wo2 = (const float*)d_in[9];
  const float* W1  = (const float*)d_in[10];
  const float* b1  = (const float*)d_in[11];
  const float* W2  = (const float*)d_in[12];
  const float* b2  = (const float*)d_in[13];
  const float* ln1g = (const float*)d_in[14];
  const float* ln1b = (const float*)d_in[15];
  const float* ln2g = (const float*)d_in[16];
  const float* ln2b = (const float*)d_in[17];
  const float* ln3g = (const float*)d_in[18];
  const float* ln3b = (const float*)d_in[19];

  char* ws = (char*)d_ws;
  size_t off = 0;
  auto alloc = [&](size_t bytes) -> void* {
    void* p = (void*)(ws + off);
    off += (bytes + 255) & ~(size_t)255;
    return p;
  };

  // weights (bf16, [N][K] transposed)
  bf16* wqkv1t = (bf16*)alloc((size_t)6 * 1536 * 512 * 2);
  bf16* wo1t   = (bf16*)alloc((size_t)6 * 512 * 512 * 2);
  bf16* wq2t   = (bf16*)alloc((size_t)6 * 512 * 512 * 2);
  bf16* wkv2t  = (bf16*)alloc((size_t)6 * 1024 * 512 * 2);
  bf16* wo2t   = (bf16*)alloc((size_t)6 * 512 * 512 * 2);
  bf16* w1t    = (bf16*)alloc((size_t)6 * 512 * 2048 * 2);
  bf16* w2t    = (bf16*)alloc((size_t)6 * 2048 * 512 * 2);
  // activations
  bf16* xb   = (bf16*)alloc((size_t)8192 * 512 * 2);
  bf16* yb   = (bf16*)alloc((size_t)8192 * 512 * 2);
  bf16* qkvb = (bf16*)alloc((size_t)8192 * 1536 * 2);
  bf16* qb   = (bf16*)alloc((size_t)8192 * 512 * 2);   // contiguous after qkvb
  bf16* kvb  = (bf16*)alloc((size_t)8192 * 1024 * 2);
  bf16* ab   = (bf16*)alloc((size_t)8192 * 512 * 2);
  bf16* h1b  = (bf16*)alloc((size_t)8192 * 512 * 2);
  bf16* h2b  = (bf16*)alloc((size_t)8192 * 512 * 2);
  float* zf  = (float*)alloc((size_t)8192 * 512 * 4);
  float* h1f = (float*)alloc((size_t)8192 * 512 * 4);
  float* h2f = (float*)alloc((size_t)8192 * 512 * 4);
  float* xf  = (float*)alloc((size_t)8192 * 512 * 4);
  bf16* f1b  = qkvb;          // aliases qkvb+qb (33.5 MB), both dead during FFN
  bf16* vt1  = (bf16*)zf;     // V^T self-attn (8.4 MB); zf dead until Wo1 gemm
  bf16* vt2  = qkvb;          // V^T cross-attn; qkvb dead after self-attn

  // --- weight prep ---
  const dim3 tb(32, 8);
  transpose_cast<<<dim3(2, 16, 48), tb, 0, stream>>>(Wq1, wqkv1t, 512, 64, 8, (size_t)1536 * 512, 0);
  transpose_cast<<<dim3(2, 16, 48), tb, 0, stream>>>(Wk1, wqkv1t, 512, 64, 8, (size_t)1536 * 512, (size_t)512 * 512);
  transpose_cast<<<dim3(2, 16, 48), tb, 0, stream>>>(Wv1, wqkv1t, 512, 64, 8, (size_t)1536 * 512, (size_t)1024 * 512);
  transpose_cast<<<dim3(16, 16, 6), tb, 0, stream>>>(Wo1, wo1t, 512, 512, 1, (size_t)512 * 512, 0);
  transpose_cast<<<dim3(2, 16, 48), tb, 0, stream>>>(Wq2, wq2t, 512, 64, 8, (size_t)512 * 512, 0);
  transpose_cast<<<dim3(2, 16, 48), tb, 0, stream>>>(Wk2, wkv2t, 512, 64, 8, (size_t)1024 * 512, 0);
  transpose_cast<<<dim3(2, 16, 48), tb, 0, stream>>>(Wv2, wkv2t, 512, 64, 8, (size_t)1024 * 512, (size_t)512 * 512);
  transpose_cast<<<dim3(16, 16, 6), tb, 0, stream>>>(Wo2, wo2t, 512, 512, 1, (size_t)512 * 512, 0);
  transpose_cast<<<dim3(64, 16, 6), tb, 0, stream>>>(W1, w1t, 512, 2048, 1, (size_t)512 * 2048, 0);
  transpose_cast<<<dim3(16, 64, 6), tb, 0, stream>>>(W2, w2t, 2048, 512, 1, (size_t)2048 * 512, 0);
  cast4<<<4096, 256, 0, stream>>>(x, xb);
  cast4<<<4096, 256, 0, stream>>>(y, yb);

  const float* curx = x;
  const bf16* curxb = xb;
  const dim3 g512(4, 64), g1024(8, 64), g1536(12, 64), gff(16, 64);
  const dim3 vtg(8, 1, 128), vtb(64, 4);

  for (int l = 0; l < 6; ++l) {
    const bf16* WQKV1 = wqkv1t + (size_t)l * 1536 * 512;
    const bf16* WO1   = wo1t   + (size_t)l * 512 * 512;
    const bf16* WQ2   = wq2t   + (size_t)l * 512 * 512;
    const bf16* WKV2  = wkv2t  + (size_t)l * 1024 * 512;
    const bf16* WO2   = wo2t   + (size_t)l * 512 * 512;
    const bf16* W1T   = w1t    + (size_t)l * 2048 * 512;
    const bf16* W2T   = w2t    + (size_t)l * 512 * 2048;

    // masked self-attention + residual + LN1
    gemm_k<0, 0, 0, 1><<<g1536, 256, 0, stream>>>(curxb, WQKV1, nullptr, qkvb,
                                                  nullptr, nullptr, 8192, 1536, 512);
    vtrans<<<vtg, vtb, 0, stream>>>(qkvb + 1024, vt1, 1536);
    attn_k<1><<<dim3(8, 8, 16), 256, 0, stream>>>(qkvb, qkvb + 512, vt1, ab, 1536, 1536);
    gemm_k<0, 0, 1, 0><<<g512, 256, 0, stream>>>(ab, WO1, zf, nullptr,
                                                 nullptr, curx, 8192, 512, 512);
    ln_k<<<2048, 256, 0, stream>>>(zf, ln1g + l * 512, ln1b + l * 512, h1f, h1b);

    // cross-attention + residual + LN2
    gemm_k<0, 0, 0, 1><<<g512, 256, 0, stream>>>(h1b, WQ2, nullptr, qb,
                                                 nullptr, nullptr, 8192, 512, 512);
    gemm_k<0, 0, 0, 1><<<g1024, 256, 0, stream>>>(yb, WKV2, nullptr, kvb,
                                                  nullptr, nullptr, 8192, 1024, 512);
    vtrans<<<vtg, vtb, 0, stream>>>(kvb + 512, vt2, 1024);
    attn_k<0><<<dim3(8, 8, 16), 256, 0, stream>>>(qb, kvb, vt2, ab, 512, 1024);
    gemm_k<0, 0, 1, 0><<<g512, 256, 0, stream>>>(ab, WO2, zf, nullptr,
                                                 nullptr, h1f, 8192, 512, 512);
    ln_k<<<2048, 256, 0, stream>>>(zf, ln2g + l * 512, ln2b + l * 512, h2f, h2b);

    // FFN + residual + LN3
    gemm_k<1, 1, 0, 1><<<gff, 256, 0, stream>>>(h2b, W1T, nullptr, f1b,
                                                b1 + l * 2048, nullptr, 8192, 2048, 512);
    gemm_k<0, 1, 1, 0><<<g512, 256, 0, stream>>>(f1b, W2T, zf, nullptr,
                                                 b2 + l * 512, h2f, 8192, 512, 2048);
    float* outf = (l == 5) ? (float*)d_out : xf;
    bf16* outb  = (l == 5) ? nullptr : xb;
    ln_k<<<2048, 256, 0, stream>>>(zf, ln3g + l * 512, ln3b + l * 512, outf, outb);
    curx = xf;
    curxb = xb;
  }
}

// Round 3
// 1593.844 us; speedup vs baseline: 1.2173x; 1.2173x over previous
//
#include <hip/hip_runtime.h>

typedef __bf16 bf16;
typedef __attribute__((ext_vector_type(8))) __bf16 bf16x8;
typedef __attribute__((ext_vector_type(4))) __bf16 bf16x4;
typedef __attribute__((ext_vector_type(4))) float f32x4;

#define GL16(gp, lp) __builtin_amdgcn_global_load_lds( \
    (const __attribute__((address_space(1))) unsigned int*)(gp), \
    (__attribute__((address_space(3))) unsigned int*)(lp), 16, 0, 0)

__device__ __forceinline__ f32x4 mfma16(bf16x8 a, bf16x8 b, f32x4 c) {
  return __builtin_amdgcn_mfma_f32_16x16x32_bf16(a, b, c, 0, 0, 0);
}

// ---------------------------------------------------------------------------
// Generic bf16 GEMM: C[M][N] = A[M][K] (bf16, row-major) * Bt[N][K]^T (bf16)
// 128x128 tile, BK=32, 4 waves (2x2 of 64x64), global_load_lds staging.
// Optional bias (fp32 [N]), residual (fp32 [M][N]), ReLU; out fp32 or bf16.
// ---------------------------------------------------------------------------
template<int RELU, int BIAS, int RES, int OUTB>
__global__ __launch_bounds__(256, 2) void gemm_k(
    const bf16* __restrict__ A, const bf16* __restrict__ Bt,
    float* __restrict__ Cf, bf16* __restrict__ Cb,
    const float* __restrict__ bias, const float* __restrict__ resid,
    int M, int N, int K)
{
  __shared__ __align__(16) bf16 Al[128 * 32];
  __shared__ __align__(16) bf16 Bl[128 * 32];
  const int tid = threadIdx.x;
  const int wid = tid >> 6, lane = tid & 63;
  const int g = lane >> 4, l16 = lane & 15;
  const int bm = blockIdx.y * 128, bn = blockIdx.x * 128;
  const int wm = (wid >> 1) * 64, wn = (wid & 1) * 64;

  const f32x4 z4 = {0.f, 0.f, 0.f, 0.f};
  f32x4 acc[4][4];
#pragma unroll
  for (int i = 0; i < 4; ++i)
#pragma unroll
    for (int j = 0; j < 4; ++j) acc[i][j] = z4;

  // staging map: per wave-pass, lane i covers LDS bytes [wid*1024 + i*16)
  const int srow = wid * 16 + (lane >> 2);   // 0..63
  const int scol = (lane & 3) * 8;           // 0,8,16,24
  const bf16* Ag = A + (size_t)(bm + srow) * K + scol;
  const bf16* Bg = Bt + (size_t)(bn + srow) * K + scol;
  bf16* Ald = &Al[srow * 32 + scol];
  bf16* Bld = &Bl[srow * 32 + scol];
  const size_t half = (size_t)64 * K;

  for (int k0 = 0; k0 < K; k0 += 32) {
    __syncthreads();
    GL16(Ag + k0, Ald);
    GL16(Ag + k0 + half, Ald + 64 * 32);
    GL16(Bg + k0, Bld);
    GL16(Bg + k0 + half, Bld + 64 * 32);
    __syncthreads();
    bf16x8 af[4], bfr[4];
#pragma unroll
    for (int mi = 0; mi < 4; ++mi)
      af[mi] = *(const bf16x8*)&Al[(wm + mi * 16 + l16) * 32 + g * 8];
#pragma unroll
    for (int ni = 0; ni < 4; ++ni)
      bfr[ni] = *(const bf16x8*)&Bl[(wn + ni * 16 + l16) * 32 + g * 8];
#pragma unroll
    for (int mi = 0; mi < 4; ++mi)
#pragma unroll
      for (int ni = 0; ni < 4; ++ni)
        acc[mi][ni] = mfma16(af[mi], bfr[ni], acc[mi][ni]);
  }

#pragma unroll
  for (int mi = 0; mi < 4; ++mi) {
#pragma unroll
    for (int ni = 0; ni < 4; ++ni) {
#pragma unroll
      for (int r = 0; r < 4; ++r) {
        const int row = bm + wm + mi * 16 + g * 4 + r;
        const int col = bn + wn + ni * 16 + l16;
        float v = acc[mi][ni][r];
        if (BIAS) v += bias[col];
        if (RES)  v += resid[(size_t)row * N + col];
        if (RELU) v = fmaxf(v, 0.f);
        const size_t idx = (size_t)row * N + col;
        if (OUTB) Cb[idx] = (bf16)v;
        else      Cf[idx] = v;
      }
    }
  }
}

// ---------------------------------------------------------------------------
// Flash attention, MFMA. One block = (b, h, 64-row q tile), 4 waves x 16 q
// rows. KV tiles of 64. K tile and V^T tile staged in LDS via global_load_lds
// (linear dest) with XOR-swizzled global source column (c ^= (row&7)<<4), so
// ds_read_b128 fragment reads (16 rows at 128B stride) are conflict-free.
// V^T precomputed globally: VT [b*8+h][64 dh][512 t]. P per-wave in LDS,
// swizzled the same way. 24KB LDS -> up to 6 blocks/CU.
// ---------------------------------------------------------------------------
template<int CAUSAL>
__global__ __launch_bounds__(256, 4) void attn_k(
    const bf16* __restrict__ Q, const bf16* __restrict__ Kg,
    const bf16* __restrict__ VT, bf16* __restrict__ O, int qs, int kvs)
{
  __shared__ __align__(16) bf16 Kl[64 * 64];        // swizzled K tile [t][dh]
  __shared__ __align__(16) bf16 Vl[64 * 64];        // swizzled VT tile [dh][t]
  __shared__ __align__(16) bf16 plb[4 * 16 * 64];   // per-wave P, swizzled
  const int tid = threadIdx.x;
  const int wid = tid >> 6, lane = tid & 63;
  const int g = lane >> 4, l16 = lane & 15;
  const int b = blockIdx.z, h = blockIdx.y;
  const int q0 = blockIdx.x * 64 + wid * 16;
  const size_t tokQ = (size_t)b * 512 + q0;

  const bf16* qp = Q + (tokQ + l16) * (size_t)qs + h * 64 + g * 8;
  const bf16x8 qf0 = *(const bf16x8*)qp;
  const bf16x8 qf1 = *(const bf16x8*)(qp + 32);

  // staging source map: issue i covers LDS bytes p = i*4096 + tid*16;
  // row r = i*32 + (tid>>3), swizzled col bytes cs = ((tid&7)*16) ^ (((tid>>3)&7)<<4)
  const int sr = tid >> 3;
  const int cs2 = ((((tid & 7) * 16) ^ ((sr & 7) << 4)) >> 1);  // bf16 elems
  const bf16* Ksrc = Kg + ((size_t)b * 512 + sr) * kvs + h * 64 + cs2;
  const bf16* Vsrc = VT + (size_t)(b * 8 + h) * 64 * 512 + (size_t)sr * 512 + cs2;
  bf16* Kd = &Kl[tid * 8];
  bf16* Vd = &Vl[tid * 8];
  bf16* pw = plb + wid * 1024;

  const f32x4 z4 = {0.f, 0.f, 0.f, 0.f};
  float m[4], ls[4];
  f32x4 o[4];
#pragma unroll
  for (int r = 0; r < 4; ++r) { m[r] = -1e30f; ls[r] = 0.f; o[r] = z4; }

  const int sw = (l16 & 7) << 4;   // byte swizzle for fragment reads
  const int ktmax = CAUSAL ? (int)blockIdx.x : 7;
  for (int kt = 0; kt <= ktmax; ++kt) {
    const int t0 = kt * 64;
    __syncthreads();   // prev-tile LDS reads complete before overwrite
    GL16(Ksrc + (size_t)t0 * kvs, Kd);
    GL16(Ksrc + (size_t)(t0 + 32) * kvs, Kd + 2048);
    GL16(Vsrc + t0, Vd);
    GL16(Vsrc + 32 * 512 + t0, Vd + 2048);
    __syncthreads();   // staged tile visible (vmcnt drained by barrier)

    // QK^T -> 4 16x16 tiles per wave (t cols t0 + jt*16 + l16)
    f32x4 sc[4];
#pragma unroll
    for (int jt = 0; jt < 4; ++jt) {
      const int rk = jt * 16 + l16;
      const bf16x8 kf0 = *(const bf16x8*)&Kl[rk * 64 + (((g * 16) ^ sw) >> 1)];
      const bf16x8 kf1 = *(const bf16x8*)&Kl[rk * 64 + (((g * 16 + 64) ^ sw) >> 1)];
      sc[jt] = mfma16(qf0, kf0, z4);
      sc[jt] = mfma16(qf1, kf1, sc[jt]);
    }
    // online softmax per row r (row q = g*4+r, col = jt*16+l16)
#pragma unroll
    for (int r = 0; r < 4; ++r) {
      const int q = g * 4 + r;
      const int srow = q0 + q;
      const int qs7 = (q & 7) << 4;
      float pv[4];
      float mx = -1e30f;
#pragma unroll
      for (int jt = 0; jt < 4; ++jt) {
        float v = sc[jt][r] * 0.125f;   // 1/sqrt(64)
        if (CAUSAL && (t0 + jt * 16 + l16) > srow) v = -1e30f;
        pv[jt] = v;
        mx = fmaxf(mx, v);
      }
#pragma unroll
      for (int msk = 8; msk; msk >>= 1) mx = fmaxf(mx, __shfl_xor(mx, msk));
      const float mn = fmaxf(m[r], mx);
      const float corr = __expf(m[r] - mn);
      float s = 0.f;
#pragma unroll
      for (int jt = 0; jt < 4; ++jt) {
        const float p = __expf(pv[jt] - mn);
        s += p;
        const int sb = (((jt * 16 + l16) * 2) ^ qs7) >> 1;
        pw[q * 64 + sb] = (bf16)p;
      }
#pragma unroll
      for (int msk = 8; msk; msk >>= 1) s += __shfl_xor(s, msk);
      ls[r] = ls[r] * corr + s;
      m[r] = mn;
#pragma unroll
      for (int j = 0; j < 4; ++j) o[j][r] *= corr;
    }
    // same-wave LDS visibility for P (no cross-wave sharing of P)
    asm volatile("s_waitcnt lgkmcnt(0)" ::: "memory");
    __builtin_amdgcn_sched_barrier(0);
    const bf16x8 pa0 = *(const bf16x8*)&pw[l16 * 64 + (((g * 16) ^ sw) >> 1)];
    const bf16x8 pa1 = *(const bf16x8*)&pw[l16 * 64 + (((g * 16 + 64) ^ sw) >> 1)];
#pragma unroll
    for (int j = 0; j < 4; ++j) {
      const int rv = j * 16 + l16;
      const bf16x8 vf0 = *(const bf16x8*)&Vl[rv * 64 + (((g * 16) ^ sw) >> 1)];
      const bf16x8 vf1 = *(const bf16x8*)&Vl[rv * 64 + (((g * 16 + 64) ^ sw) >> 1)];
      o[j] = mfma16(pa0, vf0, o[j]);
      o[j] = mfma16(pa1, vf1, o[j]);
    }
  }
#pragma unroll
  for (int r = 0; r < 4; ++r) {
    const float inv = 1.f / ls[r];
    bf16* op = O + (tokQ + g * 4 + r) * 512 + h * 64;
#pragma unroll
    for (int j = 0; j < 4; ++j) op[j * 16 + l16] = (bf16)(o[j][r] * inv);
  }
}

// ---------------------------------------------------------------------------
// V^T precompute: src = V rows [t][dh] (row stride `stride`, head offset
// applied by caller pointer), dst = VT [b*8+h][64 dh][512 t].
// Grid (8 t-tiles, 1, 128 bh), block (64,4).
// ---------------------------------------------------------------------------
__global__ void vtrans(const bf16* __restrict__ src, bf16* __restrict__ dst,
                       int stride)
{
  __shared__ bf16 t[64][65];
  const int bh = blockIdx.z;
  const int b = bh >> 3, h = bh & 7;
  const int t0 = blockIdx.x * 64;
  const int tx = threadIdx.x, ty = threadIdx.y;
  src += ((size_t)b * 512 + t0) * stride + h * 64;
  dst += (size_t)bh * 64 * 512 + t0;
#pragma unroll
  for (int j = 0; j < 64; j += 4)
    t[ty + j][tx] = src[(size_t)(ty + j) * stride + tx];
  __syncthreads();
#pragma unroll
  for (int j = 0; j < 64; j += 4)
    dst[(size_t)(ty + j) * 512 + tx] = t[tx][ty + j];
}

// ---------------------------------------------------------------------------
// LayerNorm over D=512. One wave per row; writes fp32 and (optional) bf16.
// ---------------------------------------------------------------------------
__global__ __launch_bounds__(256) void ln_k(
    const float* __restrict__ z, const float* __restrict__ gam,
    const float* __restrict__ bet, float* __restrict__ of,
    bf16* __restrict__ ob)
{
  const int wid = threadIdx.x >> 6, lane = threadIdx.x & 63;
  const int row = blockIdx.x * 4 + wid;
  const f32x4* zr = (const f32x4*)(z + (size_t)row * 512);
  const f32x4 a = zr[lane], c = zr[lane + 64];
  float s = 0.f, ss = 0.f;
#pragma unroll
  for (int e = 0; e < 4; ++e) {
    s += a[e] + c[e];
    ss += a[e] * a[e] + c[e] * c[e];
  }
#pragma unroll
  for (int msk = 32; msk; msk >>= 1) {
    s += __shfl_xor(s, msk);
    ss += __shfl_xor(ss, msk);
  }
  const float mean = s * (1.f / 512.f);
  const float var = ss * (1.f / 512.f) - mean * mean;
  const float rstd = rsqrtf(var + 1e-5f);
  const f32x4* gp = (const f32x4*)gam;
  const f32x4* bp = (const f32x4*)bet;
  const f32x4 g0 = gp[lane], g1 = gp[lane + 64];
  const f32x4 b0 = bp[lane], b1 = bp[lane + 64];
  f32x4 o0, o1;
#pragma unroll
  for (int e = 0; e < 4; ++e) {
    o0[e] = (a[e] - mean) * rstd * g0[e] + b0[e];
    o1[e] = (c[e] - mean) * rstd * g1[e] + b1[e];
  }
  f32x4* ofr = (f32x4*)(of + (size_t)row * 512);
  ofr[lane] = o0;
  ofr[lane + 64] = o1;
  if (ob) {
    bf16x4 c0, c1;
#pragma unroll
    for (int e = 0; e < 4; ++e) { c0[e] = (bf16)o0[e]; c1[e] = (bf16)o1[e]; }
    bf16x4* obr = (bf16x4*)(ob + (size_t)row * 512);
    obr[lane] = c0;
    obr[lane + 64] = c1;
  }
}

// ---------------------------------------------------------------------------
// Tiled transpose + fp32->bf16 cast: per batch z, src [R][C] -> dst [C][R].
// dst block offset = (z/bpl)*lstride + (z%bpl)*R*C + boff.
// ---------------------------------------------------------------------------
__global__ void transpose_cast(const float* __restrict__ src, bf16* __restrict__ dst,
                               int R, int C, int bpl, size_t lstride, size_t boff)
{
  __shared__ float t[32][33];
  const int z = blockIdx.z;
  src += (size_t)z * R * C;
  dst += (size_t)(z / bpl) * lstride + (size_t)(z % bpl) * ((size_t)R * C) + boff;
  const int c0 = blockIdx.x * 32, r0 = blockIdx.y * 32;
  const int tx = threadIdx.x, ty = threadIdx.y;   // (32, 8)
#pragma unroll
  for (int j = 0; j < 32; j += 8)
    t[ty + j][tx] = src[(size_t)(r0 + ty + j) * C + c0 + tx];
  __syncthreads();
#pragma unroll
  for (int j = 0; j < 32; j += 8)
    dst[(size_t)(c0 + ty + j) * R + r0 + tx] = (bf16)t[tx][ty + j];
}

__global__ void cast4(const float* __restrict__ s, bf16* __restrict__ d)
{
  const int i = blockIdx.x * 256 + threadIdx.x;
  const f32x4 v = ((const f32x4*)s)[i];
  bf16x4 c;
#pragma unroll
  for (int e = 0; e < 4; ++e) c[e] = (bf16)v[e];
  ((bf16x4*)d)[i] = c;
}

// ---------------------------------------------------------------------------
extern "C" void kernel_launch(void* const* d_in, const int* in_sizes, int n_in,
                              void* d_out, int out_size, void* d_ws, size_t ws_size,
                              hipStream_t stream)
{
  (void)in_sizes; (void)n_in; (void)out_size; (void)ws_size;
  const float* x   = (const float*)d_in[0];
  const float* y   = (const float*)d_in[1];
  const float* Wq1 = (const float*)d_in[2];
  const float* Wk1 = (const float*)d_in[3];
  const float* Wv1 = (const float*)d_in[4];
  const float* Wo1 = (const float*)d_in[5];
  const float* Wq2 = (const float*)d_in[6];
  const float* Wk2 = (const float*)d_in[7];
  const float* Wv2 = (const float*)d_in[8];
  const float* Wo2 = (const float*)d_in[9];
  const float* W1  = (const float*)d_in[10];
  const float* b1  = (const float*)d_in[11];
  const float* W2  = (const float*)d_in[12];
  const float* b2  = (const float*)d_in[13];
  const float* ln1g = (const float*)d_in[14];
  const float* ln1b = (const float*)d_in[15];
  const float* ln2g = (const float*)d_in[16];
  const float* ln2b = (const float*)d_in[17];
  const float* ln3g = (const float*)d_in[18];
  const float* ln3b = (const float*)d_in[19];

  char* ws = (char*)d_ws;
  size_t off = 0;
  auto alloc = [&](size_t bytes) -> void* {
    void* p = (void*)(ws + off);
    off += (bytes + 255) & ~(size_t)255;
    return p;
  };

  // weights (bf16, [N][K] transposed)
  bf16* wqkv1t = (bf16*)alloc((size_t)6 * 1536 * 512 * 2);
  bf16* wo1t   = (bf16*)alloc((size_t)6 * 512 * 512 * 2);
  bf16* wq2t   = (bf16*)alloc((size_t)6 * 512 * 512 * 2);
  bf16* wkv2t  = (bf16*)alloc((size_t)6 * 1024 * 512 * 2);
  bf16* wo2t   = (bf16*)alloc((size_t)6 * 512 * 512 * 2);
  bf16* w1t    = (bf16*)alloc((size_t)6 * 512 * 2048 * 2);
  bf16* w2t    = (bf16*)alloc((size_t)6 * 2048 * 512 * 2);
  // activations
  bf16* xb   = (bf16*)alloc((size_t)8192 * 512 * 2);
  bf16* yb   = (bf16*)alloc((size_t)8192 * 512 * 2);
  bf16* qkvb = (bf16*)alloc((size_t)8192 * 1536 * 2);
  bf16* qb   = (bf16*)alloc((size_t)8192 * 512 * 2);   // contiguous after qkvb
  bf16* kvb  = (bf16*)alloc((size_t)8192 * 1024 * 2);
  bf16* ab   = (bf16*)alloc((size_t)8192 * 512 * 2);
  bf16* h1b  = (bf16*)alloc((size_t)8192 * 512 * 2);
  bf16* h2b  = (bf16*)alloc((size_t)8192 * 512 * 2);
  float* zf  = (float*)alloc((size_t)8192 * 512 * 4);
  float* h1f = (float*)alloc((size_t)8192 * 512 * 4);
  float* h2f = (float*)alloc((size_t)8192 * 512 * 4);
  float* xf  = (float*)alloc((size_t)8192 * 512 * 4);
  bf16* f1b  = qkvb;          // aliases qkvb+qb (33.5 MB), both dead during FFN
  bf16* vt1  = (bf16*)zf;     // V^T self-attn (8.4 MB); zf dead until Wo1 gemm
  bf16* vt2  = qkvb;          // V^T cross-attn; qkvb dead after self-attn

  // --- weight prep ---
  const dim3 tb(32, 8);
  transpose_cast<<<dim3(2, 16, 48), tb, 0, stream>>>(Wq1, wqkv1t, 512, 64, 8, (size_t)1536 * 512, 0);
  transpose_cast<<<dim3(2, 16, 48), tb, 0, stream>>>(Wk1, wqkv1t, 512, 64, 8, (size_t)1536 * 512, (size_t)512 * 512);
  transpose_cast<<<dim3(2, 16, 48), tb, 0, stream>>>(Wv1, wqkv1t, 512, 64, 8, (size_t)1536 * 512, (size_t)1024 * 512);
  transpose_cast<<<dim3(16, 16, 6), tb, 0, stream>>>(Wo1, wo1t, 512, 512, 1, (size_t)512 * 512, 0);
  transpose_cast<<<dim3(2, 16, 48), tb, 0, stream>>>(Wq2, wq2t, 512, 64, 8, (size_t)512 * 512, 0);
  transpose_cast<<<dim3(2, 16, 48), tb, 0, stream>>>(Wk2, wkv2t, 512, 64, 8, (size_t)1024 * 512, 0);
  transpose_cast<<<dim3(2, 16, 48), tb, 0, stream>>>(Wv2, wkv2t, 512, 64, 8, (size_t)1024 * 512, (size_t)512 * 512);
  transpose_cast<<<dim3(16, 16, 6), tb, 0, stream>>>(Wo2, wo2t, 512, 512, 1, (size_t)512 * 512, 0);
  transpose_cast<<<dim3(64, 16, 6), tb, 0, stream>>>(W1, w1t, 512, 2048, 1, (size_t)512 * 2048, 0);
  transpose_cast<<<dim3(16, 64, 6), tb, 0, stream>>>(W2, w2t, 2048, 512, 1, (size_t)2048 * 512, 0);
  cast4<<<4096, 256, 0, stream>>>(x, xb);
  cast4<<<4096, 256, 0, stream>>>(y, yb);

  const float* curx = x;
  const bf16* curxb = xb;
  const dim3 g512(4, 64), g1024(8, 64), g1536(12, 64), gff(16, 64);
  const dim3 vtg(8, 1, 128), vtb(64, 4);

  for (int l = 0; l < 6; ++l) {
    const bf16* WQKV1 = wqkv1t + (size_t)l * 1536 * 512;
    const bf16* WO1   = wo1t   + (size_t)l * 512 * 512;
    const bf16* WQ2   = wq2t   + (size_t)l * 512 * 512;
    const bf16* WKV2  = wkv2t  + (size_t)l * 1024 * 512;
    const bf16* WO2   = wo2t   + (size_t)l * 512 * 512;
    const bf16* W1T   = w1t    + (size_t)l * 2048 * 512;
    const bf16* W2T   = w2t    + (size_t)l * 512 * 2048;

    // masked self-attention + residual + LN1
    gemm_k<0, 0, 0, 1><<<g1536, 256, 0, stream>>>(curxb, WQKV1, nullptr, qkvb,
                                                  nullptr, nullptr, 8192, 1536, 512);
    vtrans<<<vtg, vtb, 0, stream>>>(qkvb + 1024, vt1, 1536);
    attn_k<1><<<dim3(8, 8, 16), 256, 0, stream>>>(qkvb, qkvb + 512, vt1, ab, 1536, 1536);
    gemm_k<0, 0, 1, 0><<<g512, 256, 0, stream>>>(ab, WO1, zf, nullptr,
                                                 nullptr, curx, 8192, 512, 512);
    ln_k<<<2048, 256, 0, stream>>>(zf, ln1g + l * 512, ln1b + l * 512, h1f, h1b);

    // cross-attention + residual + LN2
    gemm_k<0, 0, 0, 1><<<g512, 256, 0, stream>>>(h1b, WQ2, nullptr, qb,
                                                 nullptr, nullptr, 8192, 512, 512);
    gemm_k<0, 0, 0, 1><<<g1024, 256, 0, stream>>>(yb, WKV2, nullptr, kvb,
                                                  nullptr, nullptr, 8192, 1024, 512);
    vtrans<<<vtg, vtb, 0, stream>>>(kvb + 512, vt2, 1024);
    attn_k<0><<<dim3(8, 8, 16), 256, 0, stream>>>(qb, kvb, vt2, ab, 512, 1024);
    gemm_k<0, 0, 1, 0><<<g512, 256, 0, stream>>>(ab, WO2, zf, nullptr,
                                                 nullptr, h1f, 8192, 512, 512);
    ln_k<<<2048, 256, 0, stream>>>(zf, ln2g + l * 512, ln2b + l * 512, h2f, h2b);

    // FFN + residual + LN3
    gemm_k<1, 1, 0, 1><<<gff, 256, 0, stream>>>(h2b, W1T, nullptr, f1b,
                                                b1 + l * 2048, nullptr, 8192, 2048, 512);
    gemm_k<0, 1, 1, 0><<<g512, 256, 0, stream>>>(f1b, W2T, zf, nullptr,
                                                 b2 + l * 512, h2f, 8192, 512, 2048);
    float* outf = (l == 5) ? (float*)d_out : xf;
    bf16* outb  = (l == 5) ? nullptr : xb;
    ln_k<<<2048, 256, 0, stream>>>(zf, ln3g + l * 512, ln3b + l * 512, outf, outb);
    curx = xf;
    curxb = xb;
  }
}

// Round 4
// 1585.581 us; speedup vs baseline: 1.2236x; 1.0052x over previous
//
#include <hip/hip_runtime.h>

typedef __bf16 bf16;
typedef __attribute__((ext_vector_type(8))) __bf16 bf16x8;
typedef __attribute__((ext_vector_type(4))) __bf16 bf16x4;
typedef __attribute__((ext_vector_type(4))) float f32x4;

#define GL16(gp, lp) __builtin_amdgcn_global_load_lds( \
    (const __attribute__((address_space(1))) unsigned int*)(gp), \
    (__attribute__((address_space(3))) unsigned int*)(lp), 16, 0, 0)

__device__ __forceinline__ f32x4 mfma16(bf16x8 a, bf16x8 b, f32x4 c) {
  return __builtin_amdgcn_mfma_f32_16x16x32_bf16(a, b, c, 0, 0, 0);
}

// ---------------------------------------------------------------------------
// Generic bf16 GEMM: C[M][N] = A[M][K] (bf16, row-major) * Bt[N][K]^T (bf16)
// 128xBN tile (BN=128 or 64), BK=32, 4 waves, double-buffered LDS with
// 1-deep prefetch: stage(k+1) issued BEFORE compute(k); single counted
// vmcnt(0)+s_barrier per K-step (T3-min 2-phase). Optional bias/resid/ReLU.
// ---------------------------------------------------------------------------
template<int BN, int RELU, int BIAS, int RES, int OUTB>
__global__ __launch_bounds__(256, 2) void gemm_k(
    const bf16* __restrict__ A, const bf16* __restrict__ Bt,
    float* __restrict__ Cf, bf16* __restrict__ Cb,
    const float* __restrict__ bias, const float* __restrict__ resid,
    int M, int N, int K)
{
  constexpr int MI = (BN == 128) ? 4 : 2;
  __shared__ __align__(16) bf16 Al[2][128 * 32];
  __shared__ __align__(16) bf16 Bl[2][BN * 32];
  const int tid = threadIdx.x;
  const int wid = tid >> 6, lane = tid & 63;
  const int g = lane >> 4, l16 = lane & 15;
  const int bm = blockIdx.y * 128, bn = blockIdx.x * BN;
  const int wm = (BN == 128) ? (wid >> 1) * 64 : wid * 32;
  const int wn = (BN == 128) ? (wid & 1) * 64 : 0;

  const f32x4 z4 = {0.f, 0.f, 0.f, 0.f};
  f32x4 acc[MI][4];
#pragma unroll
  for (int i = 0; i < MI; ++i)
#pragma unroll
    for (int j = 0; j < 4; ++j) acc[i][j] = z4;

  // staging map: one GL16 covers 64 rows x 32 cols (256 lanes x 16B)
  const int srow = tid >> 2;          // 0..63
  const int scol = (tid & 3) * 8;     // 0,8,16,24
  const bf16* Ag = A + (size_t)(bm + srow) * K + scol;
  const bf16* Bg = Bt + (size_t)(bn + srow) * K + scol;
  const size_t halfA = (size_t)64 * K;

  auto stage = [&](int sel, int k0) {
    GL16(Ag + k0, &Al[sel][srow * 32 + scol]);
    GL16(Ag + k0 + halfA, &Al[sel][(64 + srow) * 32 + scol]);
    GL16(Bg + k0, &Bl[sel][srow * 32 + scol]);
    if constexpr (BN == 128)
      GL16(Bg + k0 + halfA, &Bl[sel][(64 + srow) * 32 + scol]);
  };

  stage(0, 0);
  int cur = 0;
  for (int k0 = 0; k0 < K; k0 += 32) {
    __builtin_amdgcn_sched_barrier(0);
    asm volatile("s_waitcnt vmcnt(0)" ::: "memory");
    __builtin_amdgcn_s_barrier();
    if (k0 + 32 < K) stage(cur ^ 1, k0 + 32);   // prefetch next K-step
    bf16x8 af[MI], bfr[4];
#pragma unroll
    for (int mi = 0; mi < MI; ++mi)
      af[mi] = *(const bf16x8*)&Al[cur][(wm + mi * 16 + l16) * 32 + g * 8];
#pragma unroll
    for (int ni = 0; ni < 4; ++ni)
      bfr[ni] = *(const bf16x8*)&Bl[cur][(wn + ni * 16 + l16) * 32 + g * 8];
#pragma unroll
    for (int mi = 0; mi < MI; ++mi)
#pragma unroll
      for (int ni = 0; ni < 4; ++ni)
        acc[mi][ni] = mfma16(af[mi], bfr[ni], acc[mi][ni]);
    cur ^= 1;
  }

#pragma unroll
  for (int mi = 0; mi < MI; ++mi) {
#pragma unroll
    for (int ni = 0; ni < 4; ++ni) {
#pragma unroll
      for (int r = 0; r < 4; ++r) {
        const int row = bm + wm + mi * 16 + g * 4 + r;
        const int col = bn + wn + ni * 16 + l16;
        float v = acc[mi][ni][r];
        if (BIAS) v += bias[col];
        if (RES)  v += resid[(size_t)row * N + col];
        if (RELU) v = fmaxf(v, 0.f);
        const size_t idx = (size_t)row * N + col;
        if (OUTB) Cb[idx] = (bf16)v;
        else      Cf[idx] = v;
      }
    }
  }
}

// ---------------------------------------------------------------------------
// Flash attention, MFMA. One block = (b, h, 64-row q tile), 4 waves x 16 q
// rows. KV tiles of 64, double-buffered + 1-deep prefetch (same 2-phase
// structure as gemm_k). K/V^T staged via global_load_lds (linear dest) with
// XOR-swizzled global source column (c ^= (row&7)<<4); ds_read_b128
// fragment reads conflict-free. V^T precomputed: VT [b*8+h][64 dh][512 t].
// P per-wave in LDS, same swizzle. 40KB LDS -> 4 blocks/CU.
// ---------------------------------------------------------------------------
template<int CAUSAL>
__global__ __launch_bounds__(256, 4) void attn_k(
    const bf16* __restrict__ Q, const bf16* __restrict__ Kg,
    const bf16* __restrict__ VT, bf16* __restrict__ O, int qs, int kvs)
{
  __shared__ __align__(16) bf16 Kl[2][64 * 64];
  __shared__ __align__(16) bf16 Vl[2][64 * 64];
  __shared__ __align__(16) bf16 plb[4 * 16 * 64];
  const int tid = threadIdx.x;
  const int wid = tid >> 6, lane = tid & 63;
  const int g = lane >> 4, l16 = lane & 15;
  const int b = blockIdx.z, h = blockIdx.y;
  const int q0 = blockIdx.x * 64 + wid * 16;
  const size_t tokQ = (size_t)b * 512 + q0;

  const bf16* qp = Q + (tokQ + l16) * (size_t)qs + h * 64 + g * 8;
  const bf16x8 qf0 = *(const bf16x8*)qp;
  const bf16x8 qf1 = *(const bf16x8*)(qp + 32);

  // staging source: row sr = tid>>3, swizzled col (both-sides pattern)
  const int sr = tid >> 3;
  const int cs2 = ((((tid & 7) * 16) ^ ((sr & 7) << 4)) >> 1);  // bf16 elems
  const bf16* Ksrc = Kg + ((size_t)b * 512 + sr) * kvs + h * 64 + cs2;
  const bf16* Vsrc = VT + (size_t)(b * 8 + h) * 64 * 512 + (size_t)sr * 512 + cs2;
  bf16* pw = plb + wid * 1024;

  auto stage = [&](int sel, int t0) {
    GL16(Ksrc + (size_t)t0 * kvs, &Kl[sel][tid * 8]);
    GL16(Ksrc + (size_t)(t0 + 32) * kvs, &Kl[sel][tid * 8 + 2048]);
    GL16(Vsrc + t0, &Vl[sel][tid * 8]);
    GL16(Vsrc + 32 * 512 + t0, &Vl[sel][tid * 8 + 2048]);
  };

  const f32x4 z4 = {0.f, 0.f, 0.f, 0.f};
  float m[4], ls[4];
  f32x4 o[4];
#pragma unroll
  for (int r = 0; r < 4; ++r) { m[r] = -1e30f; ls[r] = 0.f; o[r] = z4; }

  const int sw = (l16 & 7) << 4;   // byte swizzle for fragment reads
  const int ktmax = CAUSAL ? (int)blockIdx.x : 7;
  stage(0, 0);
  int cur = 0;
  for (int kt = 0; kt <= ktmax; ++kt) {
    const int t0 = kt * 64;
    __builtin_amdgcn_sched_barrier(0);
    asm volatile("s_waitcnt vmcnt(0)" ::: "memory");
    __builtin_amdgcn_s_barrier();
    if (kt < ktmax) stage(cur ^ 1, t0 + 64);    // prefetch next KV tile

    // QK^T -> 4 16x16 tiles per wave (t cols t0 + jt*16 + l16)
    f32x4 sc[4];
#pragma unroll
    for (int jt = 0; jt < 4; ++jt) {
      const int rk = jt * 16 + l16;
      const bf16x8 kf0 = *(const bf16x8*)&Kl[cur][rk * 64 + (((g * 16) ^ sw) >> 1)];
      const bf16x8 kf1 = *(const bf16x8*)&Kl[cur][rk * 64 + (((g * 16 + 64) ^ sw) >> 1)];
      sc[jt] = mfma16(qf0, kf0, z4);
      sc[jt] = mfma16(qf1, kf1, sc[jt]);
    }
    // online softmax per row r (row q = g*4+r, col = jt*16+l16)
#pragma unroll
    for (int r = 0; r < 4; ++r) {
      const int q = g * 4 + r;
      const int srow = q0 + q;
      const int qs7 = (q & 7) << 4;
      float pv[4];
      float mx = -1e30f;
#pragma unroll
      for (int jt = 0; jt < 4; ++jt) {
        float v = sc[jt][r] * 0.125f;   // 1/sqrt(64)
        if (CAUSAL && (t0 + jt * 16 + l16) > srow) v = -1e30f;
        pv[jt] = v;
        mx = fmaxf(mx, v);
      }
#pragma unroll
      for (int msk = 8; msk; msk >>= 1) mx = fmaxf(mx, __shfl_xor(mx, msk));
      const float mn = fmaxf(m[r], mx);
      const float corr = __expf(m[r] - mn);
      float s = 0.f;
#pragma unroll
      for (int jt = 0; jt < 4; ++jt) {
        const float p = __expf(pv[jt] - mn);
        s += p;
        const int sb = (((jt * 16 + l16) * 2) ^ qs7) >> 1;
        pw[q * 64 + sb] = (bf16)p;
      }
#pragma unroll
      for (int msk = 8; msk; msk >>= 1) s += __shfl_xor(s, msk);
      ls[r] = ls[r] * corr + s;
      m[r] = mn;
#pragma unroll
      for (int j = 0; j < 4; ++j) o[j][r] *= corr;
    }
    // same-wave LDS visibility for P (no cross-wave sharing of P)
    asm volatile("s_waitcnt lgkmcnt(0)" ::: "memory");
    __builtin_amdgcn_sched_barrier(0);
    const bf16x8 pa0 = *(const bf16x8*)&pw[l16 * 64 + (((g * 16) ^ sw) >> 1)];
    const bf16x8 pa1 = *(const bf16x8*)&pw[l16 * 64 + (((g * 16 + 64) ^ sw) >> 1)];
#pragma unroll
    for (int j = 0; j < 4; ++j) {
      const int rv = j * 16 + l16;
      const bf16x8 vf0 = *(const bf16x8*)&Vl[cur][rv * 64 + (((g * 16) ^ sw) >> 1)];
      const bf16x8 vf1 = *(const bf16x8*)&Vl[cur][rv * 64 + (((g * 16 + 64) ^ sw) >> 1)];
      o[j] = mfma16(pa0, vf0, o[j]);
      o[j] = mfma16(pa1, vf1, o[j]);
    }
    cur ^= 1;
  }
#pragma unroll
  for (int r = 0; r < 4; ++r) {
    const float inv = 1.f / ls[r];
    bf16* op = O + (tokQ + g * 4 + r) * 512 + h * 64;
#pragma unroll
    for (int j = 0; j < 4; ++j) op[j * 16 + l16] = (bf16)(o[j][r] * inv);
  }
}

// ---------------------------------------------------------------------------
// V^T precompute: src = V rows [t][dh] (row stride `stride`), dst =
// VT [b*8+h][64 dh][512 t]. Grid (8 t-tiles, 1, 128 bh), block (64,4).
// ---------------------------------------------------------------------------
__global__ void vtrans(const bf16* __restrict__ src, bf16* __restrict__ dst,
                       int stride)
{
  __shared__ bf16 t[64][65];
  const int bh = blockIdx.z;
  const int b = bh >> 3, h = bh & 7;
  const int t0 = blockIdx.x * 64;
  const int tx = threadIdx.x, ty = threadIdx.y;
  src += ((size_t)b * 512 + t0) * stride + h * 64;
  dst += (size_t)bh * 64 * 512 + t0;
#pragma unroll
  for (int j = 0; j < 64; j += 4)
    t[ty + j][tx] = src[(size_t)(ty + j) * stride + tx];
  __syncthreads();
#pragma unroll
  for (int j = 0; j < 64; j += 4)
    dst[(size_t)(ty + j) * 512 + tx] = t[tx][ty + j];
}

// ---------------------------------------------------------------------------
// LayerNorm over D=512. One wave per row; writes fp32 and (optional) bf16.
// ---------------------------------------------------------------------------
__global__ __launch_bounds__(256) void ln_k(
    const float* __restrict__ z, const float* __restrict__ gam,
    const float* __restrict__ bet, float* __restrict__ of,
    bf16* __restrict__ ob)
{
  const int wid = threadIdx.x >> 6, lane = threadIdx.x & 63;
  const int row = blockIdx.x * 4 + wid;
  const f32x4* zr = (const f32x4*)(z + (size_t)row * 512);
  const f32x4 a = zr[lane], c = zr[lane + 64];
  float s = 0.f, ss = 0.f;
#pragma unroll
  for (int e = 0; e < 4; ++e) {
    s += a[e] + c[e];
    ss += a[e] * a[e] + c[e] * c[e];
  }
#pragma unroll
  for (int msk = 32; msk; msk >>= 1) {
    s += __shfl_xor(s, msk);
    ss += __shfl_xor(ss, msk);
  }
  const float mean = s * (1.f / 512.f);
  const float var = ss * (1.f / 512.f) - mean * mean;
  const float rstd = rsqrtf(var + 1e-5f);
  const f32x4* gp = (const f32x4*)gam;
  const f32x4* bp = (const f32x4*)bet;
  const f32x4 g0 = gp[lane], g1 = gp[lane + 64];
  const f32x4 b0 = bp[lane], b1 = bp[lane + 64];
  f32x4 o0, o1;
#pragma unroll
  for (int e = 0; e < 4; ++e) {
    o0[e] = (a[e] - mean) * rstd * g0[e] + b0[e];
    o1[e] = (c[e] - mean) * rstd * g1[e] + b1[e];
  }
  f32x4* ofr = (f32x4*)(of + (size_t)row * 512);
  ofr[lane] = o0;
  ofr[lane + 64] = o1;
  if (ob) {
    bf16x4 c0, c1;
#pragma unroll
    for (int e = 0; e < 4; ++e) { c0[e] = (bf16)o0[e]; c1[e] = (bf16)o1[e]; }
    bf16x4* obr = (bf16x4*)(ob + (size_t)row * 512);
    obr[lane] = c0;
    obr[lane + 64] = c1;
  }
}

// ---------------------------------------------------------------------------
// Tiled transpose + fp32->bf16 cast: per batch z, src [R][C] -> dst [C][R].
// ---------------------------------------------------------------------------
__global__ void transpose_cast(const float* __restrict__ src, bf16* __restrict__ dst,
                               int R, int C, int bpl, size_t lstride, size_t boff)
{
  __shared__ float t[32][33];
  const int z = blockIdx.z;
  src += (size_t)z * R * C;
  dst += (size_t)(z / bpl) * lstride + (size_t)(z % bpl) * ((size_t)R * C) + boff;
  const int c0 = blockIdx.x * 32, r0 = blockIdx.y * 32;
  const int tx = threadIdx.x, ty = threadIdx.y;   // (32, 8)
#pragma unroll
  for (int j = 0; j < 32; j += 8)
    t[ty + j][tx] = src[(size_t)(r0 + ty + j) * C + c0 + tx];
  __syncthreads();
#pragma unroll
  for (int j = 0; j < 32; j += 8)
    dst[(size_t)(c0 + ty + j) * R + r0 + tx] = (bf16)t[tx][ty + j];
}

__global__ void cast4(const float* __restrict__ s, bf16* __restrict__ d)
{
  const int i = blockIdx.x * 256 + threadIdx.x;
  const f32x4 v = ((const f32x4*)s)[i];
  bf16x4 c;
#pragma unroll
  for (int e = 0; e < 4; ++e) c[e] = (bf16)v[e];
  ((bf16x4*)d)[i] = c;
}

// ---------------------------------------------------------------------------
extern "C" void kernel_launch(void* const* d_in, const int* in_sizes, int n_in,
                              void* d_out, int out_size, void* d_ws, size_t ws_size,
                              hipStream_t stream)
{
  (void)in_sizes; (void)n_in; (void)out_size; (void)ws_size;
  const float* x   = (const float*)d_in[0];
  const float* y   = (const float*)d_in[1];
  const float* Wq1 = (const float*)d_in[2];
  const float* Wk1 = (const float*)d_in[3];
  const float* Wv1 = (const float*)d_in[4];
  const float* Wo1 = (const float*)d_in[5];
  const float* Wq2 = (const float*)d_in[6];
  const float* Wk2 = (const float*)d_in[7];
  const float* Wv2 = (const float*)d_in[8];
  const float* Wo2 = (const float*)d_in[9];
  const float* W1  = (const float*)d_in[10];
  const float* b1  = (const float*)d_in[11];
  const float* W2  = (const float*)d_in[12];
  const float* b2  = (const float*)d_in[13];
  const float* ln1g = (const float*)d_in[14];
  const float* ln1b = (const float*)d_in[15];
  const float* ln2g = (const float*)d_in[16];
  const float* ln2b = (const float*)d_in[17];
  const float* ln3g = (const float*)d_in[18];
  const float* ln3b = (const float*)d_in[19];

  char* ws = (char*)d_ws;
  size_t off = 0;
  auto alloc = [&](size_t bytes) -> void* {
    void* p = (void*)(ws + off);
    off += (bytes + 255) & ~(size_t)255;
    return p;
  };

  // weights (bf16, [N][K] transposed)
  bf16* wqkv1t = (bf16*)alloc((size_t)6 * 1536 * 512 * 2);
  bf16* wo1t   = (bf16*)alloc((size_t)6 * 512 * 512 * 2);
  bf16* wq2t   = (bf16*)alloc((size_t)6 * 512 * 512 * 2);
  bf16* wkv2t  = (bf16*)alloc((size_t)6 * 1024 * 512 * 2);
  bf16* wo2t   = (bf16*)alloc((size_t)6 * 512 * 512 * 2);
  bf16* w1t    = (bf16*)alloc((size_t)6 * 512 * 2048 * 2);
  bf16* w2t    = (bf16*)alloc((size_t)6 * 2048 * 512 * 2);
  // activations
  bf16* xb   = (bf16*)alloc((size_t)8192 * 512 * 2);
  bf16* yb   = (bf16*)alloc((size_t)8192 * 512 * 2);
  bf16* qkvb = (bf16*)alloc((size_t)8192 * 1536 * 2);
  bf16* qb   = (bf16*)alloc((size_t)8192 * 512 * 2);   // contiguous after qkvb
  bf16* kvb  = (bf16*)alloc((size_t)8192 * 1024 * 2);
  bf16* ab   = (bf16*)alloc((size_t)8192 * 512 * 2);
  bf16* h1b  = (bf16*)alloc((size_t)8192 * 512 * 2);
  bf16* h2b  = (bf16*)alloc((size_t)8192 * 512 * 2);
  float* zf  = (float*)alloc((size_t)8192 * 512 * 4);
  float* h1f = (float*)alloc((size_t)8192 * 512 * 4);
  float* h2f = (float*)alloc((size_t)8192 * 512 * 4);
  float* xf  = (float*)alloc((size_t)8192 * 512 * 4);
  bf16* f1b  = qkvb;          // aliases qkvb+qb (33.5 MB), both dead during FFN
  bf16* vt1  = (bf16*)zf;     // V^T self-attn (8.4 MB); zf dead until Wo1 gemm
  bf16* vt2  = qkvb;          // V^T cross-attn; qkvb dead after self-attn

  // --- weight prep ---
  const dim3 tb(32, 8);
  transpose_cast<<<dim3(2, 16, 48), tb, 0, stream>>>(Wq1, wqkv1t, 512, 64, 8, (size_t)1536 * 512, 0);
  transpose_cast<<<dim3(2, 16, 48), tb, 0, stream>>>(Wk1, wqkv1t, 512, 64, 8, (size_t)1536 * 512, (size_t)512 * 512);
  transpose_cast<<<dim3(2, 16, 48), tb, 0, stream>>>(Wv1, wqkv1t, 512, 64, 8, (size_t)1536 * 512, (size_t)1024 * 512);
  transpose_cast<<<dim3(16, 16, 6), tb, 0, stream>>>(Wo1, wo1t, 512, 512, 1, (size_t)512 * 512, 0);
  transpose_cast<<<dim3(2, 16, 48), tb, 0, stream>>>(Wq2, wq2t, 512, 64, 8, (size_t)512 * 512, 0);
  transpose_cast<<<dim3(2, 16, 48), tb, 0, stream>>>(Wk2, wkv2t, 512, 64, 8, (size_t)1024 * 512, 0);
  transpose_cast<<<dim3(2, 16, 48), tb, 0, stream>>>(Wv2, wkv2t, 512, 64, 8, (size_t)1024 * 512, (size_t)512 * 512);
  transpose_cast<<<dim3(16, 16, 6), tb, 0, stream>>>(Wo2, wo2t, 512, 512, 1, (size_t)512 * 512, 0);
  transpose_cast<<<dim3(64, 16, 6), tb, 0, stream>>>(W1, w1t, 512, 2048, 1, (size_t)512 * 2048, 0);
  transpose_cast<<<dim3(16, 64, 6), tb, 0, stream>>>(W2, w2t, 2048, 512, 1, (size_t)2048 * 512, 0);
  cast4<<<4096, 256, 0, stream>>>(x, xb);
  cast4<<<4096, 256, 0, stream>>>(y, yb);

  const float* curx = x;
  const bf16* curxb = xb;
  const dim3 g512n64(8, 64), g1024n64(16, 64), g1536(12, 64), gff(16, 64);
  const dim3 vtg(8, 1, 128), vtb(64, 4);

  for (int l = 0; l < 6; ++l) {
    const bf16* WQKV1 = wqkv1t + (size_t)l * 1536 * 512;
    const bf16* WO1   = wo1t   + (size_t)l * 512 * 512;
    const bf16* WQ2   = wq2t   + (size_t)l * 512 * 512;
    const bf16* WKV2  = wkv2t  + (size_t)l * 1024 * 512;
    const bf16* WO2   = wo2t   + (size_t)l * 512 * 512;
    const bf16* W1T   = w1t    + (size_t)l * 2048 * 512;
    const bf16* W2T   = w2t    + (size_t)l * 512 * 2048;

    // masked self-attention + residual + LN1
    gemm_k<128, 0, 0, 0, 1><<<g1536, 256, 0, stream>>>(curxb, WQKV1, nullptr, qkvb,
                                                       nullptr, nullptr, 8192, 1536, 512);
    vtrans<<<vtg, vtb, 0, stream>>>(qkvb + 1024, vt1, 1536);
    attn_k<1><<<dim3(8, 8, 16), 256, 0, stream>>>(qkvb, qkvb + 512, vt1, ab, 1536, 1536);
    gemm_k<64, 0, 0, 1, 0><<<g512n64, 256, 0, stream>>>(ab, WO1, zf, nullptr,
                                                        nullptr, curx, 8192, 512, 512);
    ln_k<<<2048, 256, 0, stream>>>(zf, ln1g + l * 512, ln1b + l * 512, h1f, h1b);

    // cross-attention + residual + LN2
    gemm_k<64, 0, 0, 0, 1><<<g512n64, 256, 0, stream>>>(h1b, WQ2, nullptr, qb,
                                                        nullptr, nullptr, 8192, 512, 512);
    gemm_k<64, 0, 0, 0, 1><<<g1024n64, 256, 0, stream>>>(yb, WKV2, nullptr, kvb,
                                                         nullptr, nullptr, 8192, 1024, 512);
    vtrans<<<vtg, vtb, 0, stream>>>(kvb + 512, vt2, 1024);
    attn_k<0><<<dim3(8, 8, 16), 256, 0, stream>>>(qb, kvb, vt2, ab, 512, 1024);
    gemm_k<64, 0, 0, 1, 0><<<g512n64, 256, 0, stream>>>(ab, WO2, zf, nullptr,
                                                        nullptr, h1f, 8192, 512, 512);
    ln_k<<<2048, 256, 0, stream>>>(zf, ln2g + l * 512, ln2b + l * 512, h2f, h2b);

    // FFN + residual + LN3
    gemm_k<128, 1, 1, 0, 1><<<gff, 256, 0, stream>>>(h2b, W1T, nullptr, f1b,
                                                     b1 + l * 2048, nullptr, 8192, 2048, 512);
    gemm_k<64, 0, 1, 1, 0><<<g512n64, 256, 0, stream>>>(f1b, W2T, zf, nullptr,
                                                        b2 + l * 512, h2f, 8192, 512, 2048);
    float* outf = (l == 5) ? (float*)d_out : xf;
    bf16* outb  = (l == 5) ? nullptr : xb;
    ln_k<<<2048, 256, 0, stream>>>(zf, ln3g + l * 512, ln3b + l * 512, outf, outb);
    curx = xf;
    curxb = xb;
  }
}

// Round 5
// 1380.976 us; speedup vs baseline: 1.4049x; 1.1482x over previous
//
#include <hip/hip_runtime.h>

typedef __bf16 bf16;
typedef __attribute__((ext_vector_type(8))) __bf16 bf16x8;
typedef __attribute__((ext_vector_type(4))) __bf16 bf16x4;
typedef __attribute__((ext_vector_type(4))) float f32x4;

#define GL16(gp, lp) __builtin_amdgcn_global_load_lds( \
    (const __attribute__((address_space(1))) unsigned int*)(gp), \
    (__attribute__((address_space(3))) unsigned int*)(lp), 16, 0, 0)

__device__ __forceinline__ f32x4 mfma16(bf16x8 a, bf16x8 b, f32x4 c) {
  return __builtin_amdgcn_mfma_f32_16x16x32_bf16(a, b, c, 0, 0, 0);
}

// ---------------------------------------------------------------------------
// Generic bf16 GEMM: C[M][N] = A[M][K] (bf16, row-major) * Bt[N][K]^T (bf16)
// 128xBN tile, BK=32, 4 waves, double-buffered LDS, 1-deep prefetch.
// XCD-aware block swizzle: same-A-panel blocks colocate on one XCD's L2.
// Optional bias (fp32 [N]), residual (bf16 [M][N]), ReLU; out fp32 or bf16.
// ---------------------------------------------------------------------------
template<int BN, int RELU, int BIAS, int RES, int OUTB>
__global__ __launch_bounds__(256, 2) void gemm_k(
    const bf16* __restrict__ A, const bf16* __restrict__ Bt,
    float* __restrict__ Cf, bf16* __restrict__ Cb,
    const float* __restrict__ bias, const bf16* __restrict__ resid,
    int M, int N, int K)
{
  constexpr int MI = (BN == 128) ? 4 : 2;
  __shared__ __align__(16) bf16 Al[2][128 * 32];
  __shared__ __align__(16) bf16 Bl[2][BN * 32];
  const int tid = threadIdx.x;
  const int wid = tid >> 6, lane = tid & 63;
  const int g = lane >> 4, l16 = lane & 15;

  // XCD swizzle: HW assigns XCD = lin%8; give each XCD a contiguous tile range
  int lin = blockIdx.x + gridDim.x * blockIdx.y;
  const int nwg = gridDim.x * gridDim.y;
  if ((nwg & 7) == 0) lin = (lin & 7) * (nwg >> 3) + (lin >> 3);
  const int bx = lin % gridDim.x, by = lin / gridDim.x;

  const int bm = by * 128, bn = bx * BN;
  const int wm = (BN == 128) ? (wid >> 1) * 64 : wid * 32;
  const int wn = (BN == 128) ? (wid & 1) * 64 : 0;

  const f32x4 z4 = {0.f, 0.f, 0.f, 0.f};
  f32x4 acc[MI][4];
#pragma unroll
  for (int i = 0; i < MI; ++i)
#pragma unroll
    for (int j = 0; j < 4; ++j) acc[i][j] = z4;

  // staging map: one GL16 covers 64 rows x 32 cols (256 lanes x 16B)
  const int srow = tid >> 2;          // 0..63
  const int scol = (tid & 3) * 8;     // 0,8,16,24
  const bf16* Ag = A + (size_t)(bm + srow) * K + scol;
  const bf16* Bg = Bt + (size_t)(bn + srow) * K + scol;
  const size_t halfA = (size_t)64 * K;

  auto stage = [&](int sel, int k0) {
    GL16(Ag + k0, &Al[sel][srow * 32 + scol]);
    GL16(Ag + k0 + halfA, &Al[sel][(64 + srow) * 32 + scol]);
    GL16(Bg + k0, &Bl[sel][srow * 32 + scol]);
    if constexpr (BN == 128)
      GL16(Bg + k0 + halfA, &Bl[sel][(64 + srow) * 32 + scol]);
  };

  stage(0, 0);
  int cur = 0;
  for (int k0 = 0; k0 < K; k0 += 32) {
    __builtin_amdgcn_sched_barrier(0);
    asm volatile("s_waitcnt vmcnt(0)" ::: "memory");
    __builtin_amdgcn_s_barrier();
    if (k0 + 32 < K) stage(cur ^ 1, k0 + 32);   // prefetch next K-step
    bf16x8 af[MI], bfr[4];
#pragma unroll
    for (int mi = 0; mi < MI; ++mi)
      af[mi] = *(const bf16x8*)&Al[cur][(wm + mi * 16 + l16) * 32 + g * 8];
#pragma unroll
    for (int ni = 0; ni < 4; ++ni)
      bfr[ni] = *(const bf16x8*)&Bl[cur][(wn + ni * 16 + l16) * 32 + g * 8];
#pragma unroll
    for (int mi = 0; mi < MI; ++mi)
#pragma unroll
      for (int ni = 0; ni < 4; ++ni)
        acc[mi][ni] = mfma16(af[mi], bfr[ni], acc[mi][ni]);
    cur ^= 1;
  }

#pragma unroll
  for (int mi = 0; mi < MI; ++mi) {
#pragma unroll
    for (int ni = 0; ni < 4; ++ni) {
#pragma unroll
      for (int r = 0; r < 4; ++r) {
        const int row = bm + wm + mi * 16 + g * 4 + r;
        const int col = bn + wn + ni * 16 + l16;
        float v = acc[mi][ni][r];
        if (BIAS) v += bias[col];
        const size_t idx = (size_t)row * N + col;
        if (RES)  v += (float)resid[idx];
        if (RELU) v = fmaxf(v, 0.f);
        if (OUTB) Cb[idx] = (bf16)v;
        else      Cf[idx] = v;
      }
    }
  }
}

// ---------------------------------------------------------------------------
// Flash attention, MFMA. One block = (b, h, 64-row q tile), 4 waves x 16 q
// rows. KV tiles of 64, double-buffered + 1-deep prefetch. K/V^T staged via
// global_load_lds (linear dest) with XOR-swizzled global source column;
// ds_read_b128 fragment reads conflict-free. V^T precomputed:
// VT [b*8+h][64 dh][512 t]. P per-wave in LDS, same swizzle.
// XCD swizzle: 8 q-tile blocks of one (b,h) colocate -> K/V L2 reuse.
// ---------------------------------------------------------------------------
template<int CAUSAL>
__global__ __launch_bounds__(256, 4) void attn_k(
    const bf16* __restrict__ Q, const bf16* __restrict__ Kg,
    const bf16* __restrict__ VT, bf16* __restrict__ O, int qs, int kvs)
{
  __shared__ __align__(16) bf16 Kl[2][64 * 64];
  __shared__ __align__(16) bf16 Vl[2][64 * 64];
  __shared__ __align__(16) bf16 plb[4 * 16 * 64];
  const int tid = threadIdx.x;
  const int wid = tid >> 6, lane = tid & 63;
  const int g = lane >> 4, l16 = lane & 15;

  // grid (8,8,16) flattened; XCD swizzle (nwg=1024, q=128)
  int lin = blockIdx.x + 8 * blockIdx.y + 64 * blockIdx.z;
  lin = (lin & 7) * 128 + (lin >> 3);
  const int qt = lin & 7, h = (lin >> 3) & 7, b = lin >> 6;

  const int q0 = qt * 64 + wid * 16;
  const size_t tokQ = (size_t)b * 512 + q0;

  const bf16* qp = Q + (tokQ + l16) * (size_t)qs + h * 64 + g * 8;
  const bf16x8 qf0 = *(const bf16x8*)qp;
  const bf16x8 qf1 = *(const bf16x8*)(qp + 32);

  // staging source: row sr = tid>>3, swizzled col (both-sides pattern)
  const int sr = tid >> 3;
  const int cs2 = ((((tid & 7) * 16) ^ ((sr & 7) << 4)) >> 1);  // bf16 elems
  const bf16* Ksrc = Kg + ((size_t)b * 512 + sr) * kvs + h * 64 + cs2;
  const bf16* Vsrc = VT + (size_t)(b * 8 + h) * 64 * 512 + (size_t)sr * 512 + cs2;
  bf16* pw = plb + wid * 1024;

  auto stage = [&](int sel, int t0) {
    GL16(Ksrc + (size_t)t0 * kvs, &Kl[sel][tid * 8]);
    GL16(Ksrc + (size_t)(t0 + 32) * kvs, &Kl[sel][tid * 8 + 2048]);
    GL16(Vsrc + t0, &Vl[sel][tid * 8]);
    GL16(Vsrc + 32 * 512 + t0, &Vl[sel][tid * 8 + 2048]);
  };

  const f32x4 z4 = {0.f, 0.f, 0.f, 0.f};
  float m[4], ls[4];
  f32x4 o[4];
#pragma unroll
  for (int r = 0; r < 4; ++r) { m[r] = -1e30f; ls[r] = 0.f; o[r] = z4; }

  const int sw = (l16 & 7) << 4;   // byte swizzle for fragment reads
  const int ktmax = CAUSAL ? qt : 7;
  stage(0, 0);
  int cur = 0;
  for (int kt = 0; kt <= ktmax; ++kt) {
    const int t0 = kt * 64;
    __builtin_amdgcn_sched_barrier(0);
    asm volatile("s_waitcnt vmcnt(0)" ::: "memory");
    __builtin_amdgcn_s_barrier();
    if (kt < ktmax) stage(cur ^ 1, t0 + 64);    // prefetch next KV tile

    // QK^T -> 4 16x16 tiles per wave (t cols t0 + jt*16 + l16)
    f32x4 sc[4];
#pragma unroll
    for (int jt = 0; jt < 4; ++jt) {
      const int rk = jt * 16 + l16;
      const bf16x8 kf0 = *(const bf16x8*)&Kl[cur][rk * 64 + (((g * 16) ^ sw) >> 1)];
      const bf16x8 kf1 = *(const bf16x8*)&Kl[cur][rk * 64 + (((g * 16 + 64) ^ sw) >> 1)];
      sc[jt] = mfma16(qf0, kf0, z4);
      sc[jt] = mfma16(qf1, kf1, sc[jt]);
    }
    // online softmax per row r (row q = g*4+r, col = jt*16+l16)
#pragma unroll
    for (int r = 0; r < 4; ++r) {
      const int q = g * 4 + r;
      const int srow = q0 + q;
      const int qs7 = (q & 7) << 4;
      float pv[4];
      float mx = -1e30f;
#pragma unroll
      for (int jt = 0; jt < 4; ++jt) {
        float v = sc[jt][r] * 0.125f;   // 1/sqrt(64)
        if (CAUSAL && (t0 + jt * 16 + l16) > srow) v = -1e30f;
        pv[jt] = v;
        mx = fmaxf(mx, v);
      }
#pragma unroll
      for (int msk = 8; msk; msk >>= 1) mx = fmaxf(mx, __shfl_xor(mx, msk));
      const float mn = fmaxf(m[r], mx);
      const float corr = __expf(m[r] - mn);
      float s = 0.f;
#pragma unroll
      for (int jt = 0; jt < 4; ++jt) {
        const float p = __expf(pv[jt] - mn);
        s += p;
        const int sb = (((jt * 16 + l16) * 2) ^ qs7) >> 1;
        pw[q * 64 + sb] = (bf16)p;
      }
#pragma unroll
      for (int msk = 8; msk; msk >>= 1) s += __shfl_xor(s, msk);
      ls[r] = ls[r] * corr + s;
      m[r] = mn;
#pragma unroll
      for (int j = 0; j < 4; ++j) o[j][r] *= corr;
    }
    // same-wave LDS visibility for P (no cross-wave sharing of P)
    asm volatile("s_waitcnt lgkmcnt(0)" ::: "memory");
    __builtin_amdgcn_sched_barrier(0);
    const bf16x8 pa0 = *(const bf16x8*)&pw[l16 * 64 + (((g * 16) ^ sw) >> 1)];
    const bf16x8 pa1 = *(const bf16x8*)&pw[l16 * 64 + (((g * 16 + 64) ^ sw) >> 1)];
#pragma unroll
    for (int j = 0; j < 4; ++j) {
      const int rv = j * 16 + l16;
      const bf16x8 vf0 = *(const bf16x8*)&Vl[cur][rv * 64 + (((g * 16) ^ sw) >> 1)];
      const bf16x8 vf1 = *(const bf16x8*)&Vl[cur][rv * 64 + (((g * 16 + 64) ^ sw) >> 1)];
      o[j] = mfma16(pa0, vf0, o[j]);
      o[j] = mfma16(pa1, vf1, o[j]);
    }
    cur ^= 1;
  }
#pragma unroll
  for (int r = 0; r < 4; ++r) {
    const float inv = 1.f / ls[r];
    bf16* op = O + (tokQ + g * 4 + r) * 512 + h * 64;
#pragma unroll
    for (int j = 0; j < 4; ++j) op[j * 16 + l16] = (bf16)(o[j][r] * inv);
  }
}

// ---------------------------------------------------------------------------
// V^T precompute: src = V rows [t][dh] (row stride `stride`), dst =
// VT [b*8+h][64 dh][512 t]. Grid (8 t-tiles, 1, 128 bh), block (64,4).
// ---------------------------------------------------------------------------
__global__ void vtrans(const bf16* __restrict__ src, bf16* __restrict__ dst,
                       int stride)
{
  __shared__ bf16 t[64][65];
  const int bh = blockIdx.z;
  const int b = bh >> 3, h = bh & 7;
  const int t0 = blockIdx.x * 64;
  const int tx = threadIdx.x, ty = threadIdx.y;
  src += ((size_t)b * 512 + t0) * stride + h * 64;
  dst += (size_t)bh * 64 * 512 + t0;
#pragma unroll
  for (int j = 0; j < 64; j += 4)
    t[ty + j][tx] = src[(size_t)(ty + j) * stride + tx];
  __syncthreads();
#pragma unroll
  for (int j = 0; j < 64; j += 4)
    dst[(size_t)(ty + j) * 512 + tx] = t[tx][ty + j];
}

// ---------------------------------------------------------------------------
// LayerNorm over D=512. One wave per row; fp32 math; writes bf16 and/or fp32.
// ---------------------------------------------------------------------------
__global__ __launch_bounds__(256) void ln_k(
    const float* __restrict__ z, const float* __restrict__ gam,
    const float* __restrict__ bet, float* __restrict__ of,
    bf16* __restrict__ ob)
{
  const int wid = threadIdx.x >> 6, lane = threadIdx.x & 63;
  const int row = blockIdx.x * 4 + wid;
  const f32x4* zr = (const f32x4*)(z + (size_t)row * 512);
  const f32x4 a = zr[lane], c = zr[lane + 64];
  float s = 0.f, ss = 0.f;
#pragma unroll
  for (int e = 0; e < 4; ++e) {
    s += a[e] + c[e];
    ss += a[e] * a[e] + c[e] * c[e];
  }
#pragma unroll
  for (int msk = 32; msk; msk >>= 1) {
    s += __shfl_xor(s, msk);
    ss += __shfl_xor(ss, msk);
  }
  const float mean = s * (1.f / 512.f);
  const float var = ss * (1.f / 512.f) - mean * mean;
  const float rstd = rsqrtf(var + 1e-5f);
  const f32x4* gp = (const f32x4*)gam;
  const f32x4* bp = (const f32x4*)bet;
  const f32x4 g0 = gp[lane], g1 = gp[lane + 64];
  const f32x4 b0 = bp[lane], b1 = bp[lane + 64];
  f32x4 o0, o1;
#pragma unroll
  for (int e = 0; e < 4; ++e) {
    o0[e] = (a[e] - mean) * rstd * g0[e] + b0[e];
    o1[e] = (c[e] - mean) * rstd * g1[e] + b1[e];
  }
  if (of) {
    f32x4* ofr = (f32x4*)(of + (size_t)row * 512);
    ofr[lane] = o0;
    ofr[lane + 64] = o1;
  }
  if (ob) {
    bf16x4 c0, c1;
#pragma unroll
    for (int e = 0; e < 4; ++e) { c0[e] = (bf16)o0[e]; c1[e] = (bf16)o1[e]; }
    bf16x4* obr = (bf16x4*)(ob + (size_t)row * 512);
    obr[lane] = c0;
    obr[lane + 64] = c1;
  }
}

// ---------------------------------------------------------------------------
// Tiled transpose + fp32->bf16 cast: per batch z, src [R][C] -> dst [C][R].
// ---------------------------------------------------------------------------
__global__ void transpose_cast(const float* __restrict__ src, bf16* __restrict__ dst,
                               int R, int C, int bpl, size_t lstride, size_t boff)
{
  __shared__ float t[32][33];
  const int z = blockIdx.z;
  src += (size_t)z * R * C;
  dst += (size_t)(z / bpl) * lstride + (size_t)(z % bpl) * ((size_t)R * C) + boff;
  const int c0 = blockIdx.x * 32, r0 = blockIdx.y * 32;
  const int tx = threadIdx.x, ty = threadIdx.y;   // (32, 8)
#pragma unroll
  for (int j = 0; j < 32; j += 8)
    t[ty + j][tx] = src[(size_t)(r0 + ty + j) * C + c0 + tx];
  __syncthreads();
#pragma unroll
  for (int j = 0; j < 32; j += 8)
    dst[(size_t)(c0 + ty + j) * R + r0 + tx] = (bf16)t[tx][ty + j];
}

__global__ void cast4(const float* __restrict__ s, bf16* __restrict__ d)
{
  const int i = blockIdx.x * 256 + threadIdx.x;
  const f32x4 v = ((const f32x4*)s)[i];
  bf16x4 c;
#pragma unroll
  for (int e = 0; e < 4; ++e) c[e] = (bf16)v[e];
  ((bf16x4*)d)[i] = c;
}

// ---------------------------------------------------------------------------
extern "C" void kernel_launch(void* const* d_in, const int* in_sizes, int n_in,
                              void* d_out, int out_size, void* d_ws, size_t ws_size,
                              hipStream_t stream)
{
  (void)in_sizes; (void)n_in; (void)out_size; (void)ws_size;
  const float* x   = (const float*)d_in[0];
  const float* y   = (const float*)d_in[1];
  const float* Wq1 = (const float*)d_in[2];
  const float* Wk1 = (const float*)d_in[3];
  const float* Wv1 = (const float*)d_in[4];
  const float* Wo1 = (const float*)d_in[5];
  const float* Wq2 = (const float*)d_in[6];
  const float* Wk2 = (const float*)d_in[7];
  const float* Wv2 = (const float*)d_in[8];
  const float* Wo2 = (const float*)d_in[9];
  const float* W1  = (const float*)d_in[10];
  const float* b1  = (const float*)d_in[11];
  const float* W2  = (const float*)d_in[12];
  const float* b2  = (const float*)d_in[13];
  const float* ln1g = (const float*)d_in[14];
  const float* ln1b = (const float*)d_in[15];
  const float* ln2g = (const float*)d_in[16];
  const float* ln2b = (const float*)d_in[17];
  const float* ln3g = (const float*)d_in[18];
  const float* ln3b = (const float*)d_in[19];

  char* ws = (char*)d_ws;
  size_t off = 0;
  auto alloc = [&](size_t bytes) -> void* {
    void* p = (void*)(ws + off);
    off += (bytes + 255) & ~(size_t)255;
    return p;
  };

  // weights (bf16, [N][K] transposed)
  bf16* wqkv1t = (bf16*)alloc((size_t)6 * 1536 * 512 * 2);
  bf16* wo1t   = (bf16*)alloc((size_t)6 * 512 * 512 * 2);
  bf16* wq2t   = (bf16*)alloc((size_t)6 * 512 * 512 * 2);
  bf16* wkv2t  = (bf16*)alloc((size_t)6 * 1024 * 512 * 2);
  bf16* wo2t   = (bf16*)alloc((size_t)6 * 512 * 512 * 2);
  bf16* w1t    = (bf16*)alloc((size_t)6 * 512 * 2048 * 2);
  bf16* w2t    = (bf16*)alloc((size_t)6 * 2048 * 512 * 2);
  // activations
  bf16* xb   = (bf16*)alloc((size_t)8192 * 512 * 2);
  bf16* yb   = (bf16*)alloc((size_t)8192 * 512 * 2);
  bf16* qkvb = (bf16*)alloc((size_t)8192 * 1536 * 2);
  bf16* qb   = (bf16*)alloc((size_t)8192 * 512 * 2);   // contiguous after qkvb
  bf16* kvb  = (bf16*)alloc((size_t)8192 * 1024 * 2);
  bf16* ab   = (bf16*)alloc((size_t)8192 * 512 * 2);
  bf16* h1b  = (bf16*)alloc((size_t)8192 * 512 * 2);
  bf16* h2b  = (bf16*)alloc((size_t)8192 * 512 * 2);
  float* zf  = (float*)alloc((size_t)8192 * 512 * 4);
  bf16* vt1  = (bf16*)alloc((size_t)8192 * 512 * 2);   // V^T self-attn
  bf16* f1b  = qkvb;          // aliases qkvb+qb (33.5 MB), both dead during FFN
  bf16* vt2  = qkvb;          // V^T cross-attn; qkvb dead after self-attn

  // --- weight prep ---
  const dim3 tb(32, 8);
  transpose_cast<<<dim3(2, 16, 48), tb, 0, stream>>>(Wq1, wqkv1t, 512, 64, 8, (size_t)1536 * 512, 0);
  transpose_cast<<<dim3(2, 16, 48), tb, 0, stream>>>(Wk1, wqkv1t, 512, 64, 8, (size_t)1536 * 512, (size_t)512 * 512);
  transpose_cast<<<dim3(2, 16, 48), tb, 0, stream>>>(Wv1, wqkv1t, 512, 64, 8, (size_t)1536 * 512, (size_t)1024 * 512);
  transpose_cast<<<dim3(16, 16, 6), tb, 0, stream>>>(Wo1, wo1t, 512, 512, 1, (size_t)512 * 512, 0);
  transpose_cast<<<dim3(2, 16, 48), tb, 0, stream>>>(Wq2, wq2t, 512, 64, 8, (size_t)512 * 512, 0);
  transpose_cast<<<dim3(2, 16, 48), tb, 0, stream>>>(Wk2, wkv2t, 512, 64, 8, (size_t)1024 * 512, 0);
  transpose_cast<<<dim3(2, 16, 48), tb, 0, stream>>>(Wv2, wkv2t, 512, 64, 8, (size_t)1024 * 512, (size_t)512 * 512);
  transpose_cast<<<dim3(16, 16, 6), tb, 0, stream>>>(Wo2, wo2t, 512, 512, 1, (size_t)512 * 512, 0);
  transpose_cast<<<dim3(64, 16, 6), tb, 0, stream>>>(W1, w1t, 512, 2048, 1, (size_t)512 * 2048, 0);
  transpose_cast<<<dim3(16, 64, 6), tb, 0, stream>>>(W2, w2t, 2048, 512, 1, (size_t)2048 * 512, 0);
  cast4<<<4096, 256, 0, stream>>>(x, xb);
  cast4<<<4096, 256, 0, stream>>>(y, yb);

  const bf16* curxb = xb;
  const dim3 g512n64(8, 64), g1024n64(16, 64), g1536(12, 64), gff(16, 64);
  const dim3 vtg(8, 1, 128), vtb(64, 4);

  for (int l = 0; l < 6; ++l) {
    const bf16* WQKV1 = wqkv1t + (size_t)l * 1536 * 512;
    const bf16* WO1   = wo1t   + (size_t)l * 512 * 512;
    const bf16* WQ2   = wq2t   + (size_t)l * 512 * 512;
    const bf16* WKV2  = wkv2t  + (size_t)l * 1024 * 512;
    const bf16* WO2   = wo2t   + (size_t)l * 512 * 512;
    const bf16* W1T   = w1t    + (size_t)l * 2048 * 512;
    const bf16* W2T   = w2t    + (size_t)l * 512 * 2048;

    // masked self-attention + residual + LN1
    gemm_k<128, 0, 0, 0, 1><<<g1536, 256, 0, stream>>>(curxb, WQKV1, nullptr, qkvb,
                                                       nullptr, nullptr, 8192, 1536, 512);
    vtrans<<<vtg, vtb, 0, stream>>>(qkvb + 1024, vt1, 1536);
    attn_k<1><<<dim3(8, 8, 16), 256, 0, stream>>>(qkvb, qkvb + 512, vt1, ab, 1536, 1536);
    gemm_k<64, 0, 0, 1, 0><<<g512n64, 256, 0, stream>>>(ab, WO1, zf, nullptr,
                                                        nullptr, curxb, 8192, 512, 512);
    ln_k<<<2048, 256, 0, stream>>>(zf, ln1g + l * 512, ln1b + l * 512, nullptr, h1b);

    // cross-attention + residual + LN2
    gemm_k<64, 0, 0, 0, 1><<<g512n64, 256, 0, stream>>>(h1b, WQ2, nullptr, qb,
                                                        nullptr, nullptr, 8192, 512, 512);
    gemm_k<64, 0, 0, 0, 1><<<g1024n64, 256, 0, stream>>>(yb, WKV2, nullptr, kvb,
                                                         nullptr, nullptr, 8192, 1024, 512);
    vtrans<<<vtg, vtb, 0, stream>>>(kvb + 512, vt2, 1024);
    attn_k<0><<<dim3(8, 8, 16), 256, 0, stream>>>(qb, kvb, vt2, ab, 512, 1024);
    gemm_k<64, 0, 0, 1, 0><<<g512n64, 256, 0, stream>>>(ab, WO2, zf, nullptr,
                                                        nullptr, h1b, 8192, 512, 512);
    ln_k<<<2048, 256, 0, stream>>>(zf, ln2g + l * 512, ln2b + l * 512, nullptr, h2b);

    // FFN + residual + LN3
    gemm_k<128, 1, 1, 0, 1><<<gff, 256, 0, stream>>>(h2b, W1T, nullptr, f1b,
                                                     b1 + l * 2048, nullptr, 8192, 2048, 512);
    gemm_k<64, 0, 1, 1, 0><<<g512n64, 256, 0, stream>>>(f1b, W2T, zf, nullptr,
                                                        b2 + l * 512, h2b, 8192, 512, 2048);
    float* outf = (l == 5) ? (float*)d_out : nullptr;
    bf16* outb  = (l == 5) ? nullptr : xb;
    ln_k<<<2048, 256, 0, stream>>>(zf, ln3g + l * 512, ln3b + l * 512, outf, outb);
    curxb = xb;
  }
}